// Round 3
// baseline (652.893 us; speedup 1.0000x reference)
//
#include <hip/hip_runtime.h>
#include <hip/hip_bf16.h>
#include <stdint.h>

#define LVLS 16
#define TSZ  524288          // hash table size per level (2^19)
#define TMASK 0x7FFFFu
#define NPTS 524288
#define P1 2654435761u
#define P2 805459861u
#define P3 3674653429u

// floor(16 * 1.5^l), hardcoded
__constant__ float RES_TAB[16] = {
    16.f, 24.f, 36.f, 54.f, 81.f, 121.f, 182.f, 273.f,
    410.f, 615.f, 922.f, 1383.f, 2075.f, 3113.f, 4670.f, 7006.f};

using f16x8 = __attribute__((ext_vector_type(8))) _Float16;
using f32x4 = __attribute__((ext_vector_type(4))) float;

union PackF16 { uint32_t u; _Float16 h[2]; };

constexpr int PS = 72;    // scratch pitch (64 cols + 8 pad)  -> 2-way-free banks
constexpr int PF = 136;   // feature pitch (128 cols + 8 pad)

// ---------------------------------------------------------------------------
// Kernel W: swizzle weights (fp32 [K][N] row-major) into f16 B-fragment layout
// for mfma_f32_16x16x32_f16 (verified r1/r2):
//   dst[((ct*KC+kc)*64+lane)*8+j] = W[kc*32+(lane>>4)*8+j][ct*16+(lane&15)]
// ---------------------------------------------------------------------------
struct WPtrs { const float* p[11]; };

__global__ void k_weights(WPtrs wp, _Float16* __restrict__ dst) {
    int id = blockIdx.x * 256 + threadIdx.x;
    if (id >= 69632) return;
    const int OFF[16] = {0,2048,6144,10240,14336,18432,20480,24576,28672,
                         32768,36864,45056,49152,57344,65536,69632};
    const int KK[15]  = {32,64,64,64,64,32,64,64,64,64,128,64,64,128,64};
    const int NN[15]  = {64,64,64,64,64,64,64,64,64,64,64,64,128,64,64};
    const int PSEL[15]= {0,1,1,1,2,3,4,4,4,5,6,7,8,9,10};
    const int POFF[15]= {0,0,4096,8192,0,0,0,4096,8192,0,0,0,0,0,0};
    int m = 0;
    while (id >= OFF[m+1]) m++;
    int local = id - OFF[m];
    int j    = local & 7;
    int lane = (local >> 3) & 63;
    int blk  = local >> 9;
    int KC   = KK[m] >> 5;
    int ct   = blk / KC;
    int kc   = blk - ct * KC;
    int k    = kc*32 + ((lane>>4)<<3) + j;
    int n    = ct*16 + (lane & 15);
    const float* src = wp.p[PSEL[m]] + POFF[m];
    dst[id] = (_Float16)src[k * NN[m] + n];
}

// ---------------------------------------------------------------------------
// Kernel T: combined f16 table. Tc[l][i] = { static(i), t-blended dynamic }:
//   dynamic = (1-ft)*td[l][i^h0] + ft*td[l][i^h1]  (t-corner hashes baked in)
// ---------------------------------------------------------------------------
__global__ void k_tables(const float* __restrict__ ts, const float* __restrict__ td,
                         const float* __restrict__ tptr, uint2* __restrict__ Tc) {
    int id = blockIdx.x * 256 + threadIdx.x;   // 0 .. LVLS*TSZ-1
    int l = id >> 19, i = id & TMASK;
    float2 sv = ((const float2*)ts)[id];
    float res = RES_TAB[l];
    float tv  = tptr[0];
    float pt  = tv * res;
    float fpt = floorf(pt);
    float ft  = pt - fpt;
    uint32_t ut = (uint32_t)(int)fpt;
    uint32_t h0 = (ut * P3) & TMASK;
    uint32_t h1 = ((ut + 1u) * P3) & TMASK;
    const float2* tdl = (const float2*)td + (size_t)l * TSZ;
    float2 a = tdl[i ^ h0];
    float2 b = tdl[i ^ h1];
    PackF16 o0, o1;
    o0.h[0] = (_Float16)sv.x; o0.h[1] = (_Float16)sv.y;
    o1.h[0] = (_Float16)((1.f - ft) * a.x + ft * b.x);
    o1.h[1] = (_Float16)((1.f - ft) * a.y + ft * b.y);
    Tc[id] = make_uint2(o0.u, o1.u);
}

// ---------------------------------------------------------------------------
// Kernel E: hash-grid encode, level-per-XCD sharded (blockIdx%8 = XCD class,
// class c owns levels 2c,2c+1 -> live table slice 4 MiB = one XCD L2).
// x loads and Enc stores are NONTEMPORAL so the L2 holds only the table.
// 2 points per iteration -> 16 outstanding 8B gathers.
// ---------------------------------------------------------------------------
__launch_bounds__(256)
__global__ void k_encode(const float* __restrict__ x,
                         const uint2* __restrict__ Tc,
                         uint32_t* __restrict__ EncS, uint32_t* __restrict__ EncD) {
    int tid  = threadIdx.x;
    int xcd  = blockIdx.x & 7;
    int gt   = (blockIdx.x >> 3) * 256 + tid;   // 0..65535 within class
#pragma unroll
    for (int pass = 0; pass < 2; pass++) {
        int l = xcd * 2 + pass;
        float res = RES_TAB[l];
        const uint2* tcl = Tc + (size_t)l * TSZ;
        uint32_t* es = EncS + (size_t)l * NPTS;
        uint32_t* ed = EncD + (size_t)l * NPTS;
        for (int q = 0; q < 4; q++) {
            int p[2] = { gt + (2*q) * 65536, gt + (2*q+1) * 65536 };
            uint32_t idx[2][8];
            float wxa[2][2], wya[2][2], wza[2][2];
#pragma unroll
            for (int b = 0; b < 2; b++) {
                float px = __builtin_nontemporal_load(x + p[b]*3 + 0) * res;
                float py = __builtin_nontemporal_load(x + p[b]*3 + 1) * res;
                float pz = __builtin_nontemporal_load(x + p[b]*3 + 2) * res;
                float fx = floorf(px), fy = floorf(py), fz = floorf(pz);
                float wx = px-fx, wy = py-fy, wz = pz-fz;
                uint32_t ux = (uint32_t)(int)fx, uy = (uint32_t)(int)fy, uz = (uint32_t)(int)fz;
                uint32_t hx[2] = {ux, ux + 1u};
                uint32_t hy[2] = {uy * P1, (uy + 1u) * P1};
                uint32_t hz[2] = {uz * P2, (uz + 1u) * P2};
#pragma unroll
                for (int c = 0; c < 8; c++)
                    idx[b][c] = (hx[c&1] ^ hy[(c>>1)&1] ^ hz[c>>2]) & TMASK;
                wxa[b][0] = 1.f-wx; wxa[b][1] = wx;
                wya[b][0] = 1.f-wy; wya[b][1] = wy;
                wza[b][0] = 1.f-wz; wza[b][1] = wz;
            }
            uint2 v[2][8];
#pragma unroll
            for (int b = 0; b < 2; b++)
#pragma unroll
                for (int c = 0; c < 8; c++)
                    v[b][c] = tcl[idx[b][c]];
#pragma unroll
            for (int b = 0; b < 2; b++) {
                float sA0 = 0.f, sA1 = 0.f, sD0 = 0.f, sD1 = 0.f;
#pragma unroll
                for (int c = 0; c < 8; c++) {
                    float w = wxa[b][c&1] * wya[b][(c>>1)&1] * wza[b][c>>2];
                    PackF16 s, d; s.u = v[b][c].x; d.u = v[b][c].y;
                    sA0 += w * (float)s.h[0]; sA1 += w * (float)s.h[1];
                    sD0 += w * (float)d.h[0]; sD1 += w * (float)d.h[1];
                }
                PackF16 o;
                o.h[0] = (_Float16)sA0; o.h[1] = (_Float16)sA1;
                __builtin_nontemporal_store(o.u, es + p[b]);
                o.h[0] = (_Float16)sD0; o.h[1] = (_Float16)sD1;
                __builtin_nontemporal_store(o.u, ed + p[b]);
            }
        }
    }
}

// ---------------------------------------------------------------------------
// Kernel M: barrier-free MLP, wave-private 16-point tiles, in-wave lgkmcnt
// ordering only. Static & dynamic encoder chains interleaved for ILP.
// LDS/block = 4*(16*PS + 16*PF)*2B = 26.6 KB -> 6 blocks/CU.
// Fragment maps: A[m=lane&15][k=quad*8+j], B frag from k_weights,
// D row=quad*4+i, col=lane&15.
// ---------------------------------------------------------------------------
__device__ __forceinline__ void wait_lds() {
    asm volatile("s_waitcnt lgkmcnt(0)" ::: "memory");
}

template<int KC, bool RELU>
__device__ __forceinline__ void mm_to_lds(const f16x8* a, const f16x8* __restrict__ W,
                                          _Float16* buf, int pitch, int m, int quad, int lane) {
#pragma unroll
    for (int ct = 0; ct < 4; ct++) {
        f32x4 acc = {0.f, 0.f, 0.f, 0.f};
#pragma unroll
        for (int kc = 0; kc < KC; kc++)
            acc = __builtin_amdgcn_mfma_f32_16x16x32_f16(a[kc], W[(ct*KC+kc)*64+lane], acc, 0, 0, 0);
#pragma unroll
        for (int i = 0; i < 4; i++) {
            float v = acc[i];
            if (RELU) v = fmaxf(v, 0.f);
            buf[(quad*4+i)*pitch + ct*16 + m] = (_Float16)v;
        }
    }
}

// Linear-out layer: write D to buf AND keep packed copy in regs (for blend)
template<int KC>
__device__ __forceinline__ void mm_keep(const f16x8* a, const f16x8* __restrict__ W,
                                        _Float16* buf, int pitch, PackF16* P,
                                        int m, int quad, int lane) {
#pragma unroll
    for (int ct = 0; ct < 4; ct++) {
        f32x4 acc = {0.f, 0.f, 0.f, 0.f};
#pragma unroll
        for (int kc = 0; kc < KC; kc++)
            acc = __builtin_amdgcn_mfma_f32_16x16x32_f16(a[kc], W[(ct*KC+kc)*64+lane], acc, 0, 0, 0);
#pragma unroll
        for (int ih = 0; ih < 2; ih++) {
            PackF16 pk;
            pk.h[0] = (_Float16)acc[ih*2+0];
            pk.h[1] = (_Float16)acc[ih*2+1];
            P[ct*2+ih] = pk;
            buf[(quad*4+ih*2+0)*pitch + ct*16 + m] = pk.h[0];
            buf[(quad*4+ih*2+1)*pitch + ct*16 + m] = pk.h[1];
        }
    }
}

template<int KC>
__device__ __forceinline__ void lds_to_afrag(const _Float16* buf, int pitch,
                                             f16x8* a, int m, int quad) {
#pragma unroll
    for (int kc = 0; kc < KC; kc++)
        a[kc] = *(const f16x8*)(buf + m*pitch + kc*32 + quad*8);
}

__device__ __forceinline__ void load_enc(const uint32_t* __restrict__ Enc,
                                         int pbase, int m, int quad, f16x8* a) {
    union { uint32_t u[4]; f16x8 v; } cv;
#pragma unroll
    for (int jj = 0; jj < 4; jj++)
        cv.u[jj] = Enc[(size_t)(quad*4+jj) * NPTS + pbase + m];
    a[0] = cv.v;
}

__launch_bounds__(256)
__global__ void k_mlp(const uint32_t* __restrict__ EncS, const uint32_t* __restrict__ EncD,
                      const _Float16* __restrict__ Wfrag, const float* __restrict__ alphap,
                      const float* __restrict__ w2out, float* __restrict__ out) {
    __shared__ _Float16 Sbuf[4][16*PS];
    __shared__ _Float16 Fbuf[4][16*PF];
    int tid  = threadIdx.x;
    int wave = tid >> 6, lane = tid & 63;
    int m = lane & 15, quad = lane >> 4;
    int pbase = blockIdx.x * 64 + wave * 16;
    _Float16* S = Sbuf[wave];
    _Float16* F = Fbuf[wave];
    _Float16* D = F + 64;          // dynamic chain scratch = F cols 64..127
    const f16x8* W8 = (const f16x8*)Wfrag;

    f16x8 aS[4], aD[4];
    PackF16 sP[8], dP[8];

    // ---- static & dynamic encoder MLPs, interleaved ----
    load_enc(EncS, pbase, m, quad, aS);
    load_enc(EncD, pbase, m, quad, aD);
    mm_to_lds<1, true>(aS, W8 + 0,    S, PS, m, quad, lane);
    mm_to_lds<1, true>(aD, W8 + 2304, D, PF, m, quad, lane); wait_lds();
    lds_to_afrag<2>(S, PS, aS, m, quad);
    lds_to_afrag<2>(D, PF, aD, m, quad);
    mm_to_lds<2, true>(aS, W8 + 256,  S, PS, m, quad, lane);
    mm_to_lds<2, true>(aD, W8 + 2560, D, PF, m, quad, lane); wait_lds();
    lds_to_afrag<2>(S, PS, aS, m, quad);
    lds_to_afrag<2>(D, PF, aD, m, quad);
    mm_to_lds<2, true>(aS, W8 + 768,  S, PS, m, quad, lane);
    mm_to_lds<2, true>(aD, W8 + 3072, D, PF, m, quad, lane); wait_lds();
    lds_to_afrag<2>(S, PS, aS, m, quad);
    lds_to_afrag<2>(D, PF, aD, m, quad);
    mm_to_lds<2, true>(aS, W8 + 1280, S, PS, m, quad, lane);
    mm_to_lds<2, true>(aD, W8 + 3584, D, PF, m, quad, lane); wait_lds();
    lds_to_afrag<2>(S, PS, aS, m, quad);
    lds_to_afrag<2>(D, PF, aD, m, quad);
    mm_keep<2>(aS, W8 + 1792, F, PF, sP, m, quad, lane);   // F cols 0..63
    mm_keep<2>(aD, W8 + 4096, D, PF, dP, m, quad, lane);   // F cols 64..127
    wait_lds();
    // ---- mlp1: 128->64 relu, 64->64 relu ----
    f16x8 a[4];
    lds_to_afrag<4>(F, PF, a, m, quad);
    mm_to_lds<4, true>(a, W8 + 4608, S, PS, m, quad, lane); wait_lds();
    lds_to_afrag<2>(S, PS, a, m, quad);
    mm_to_lds<2, true>(a, W8 + 5632, S, PS, m, quad, lane); wait_lds();
    lds_to_afrag<2>(S, PS, a, m, quad);
    // ---- out1 (64->128) fused with skip blend, write F in place ----
    float alpha = alphap[0];
#pragma unroll
    for (int ct = 0; ct < 8; ct++) {
        f32x4 acc = {0.f, 0.f, 0.f, 0.f};
#pragma unroll
        for (int kc = 0; kc < 2; kc++)
            acc = __builtin_amdgcn_mfma_f32_16x16x32_f16(a[kc], W8[6144 + (ct*2+kc)*64+lane], acc, 0, 0, 0);
#pragma unroll
        for (int i = 0; i < 4; i++) {
            float f = (ct < 4) ? (float)sP[ct*2 + (i>>1)].h[i&1]
                               : (float)dP[(ct-4)*2 + (i>>1)].h[i&1];
            F[(quad*4+i)*PF + ct*16 + m] = (_Float16)(alpha * acc[i] + (1.f - alpha) * f);
        }
    }
    wait_lds();
    // ---- mlp2: 128->64 relu, 64->64 relu, dot w2_out ----
    lds_to_afrag<4>(F, PF, a, m, quad);
    mm_to_lds<4, true>(a, W8 + 7168, S, PS, m, quad, lane); wait_lds();
    lds_to_afrag<2>(S, PS, a, m, quad);
    float rsum[4] = {0.f, 0.f, 0.f, 0.f};
#pragma unroll
    for (int ct = 0; ct < 4; ct++) {
        f32x4 acc = {0.f, 0.f, 0.f, 0.f};
#pragma unroll
        for (int kc = 0; kc < 2; kc++)
            acc = __builtin_amdgcn_mfma_f32_16x16x32_f16(a[kc], W8[8192 + (ct*2+kc)*64+lane], acc, 0, 0, 0);
        float wv = w2out[ct*16 + m];
#pragma unroll
        for (int i = 0; i < 4; i++)
            rsum[i] += fmaxf(acc[i], 0.f) * wv;
    }
#pragma unroll
    for (int off = 1; off < 16; off <<= 1) {
#pragma unroll
        for (int i = 0; i < 4; i++)
            rsum[i] += __shfl_xor(rsum[i], off, 64);
    }
    if (m == 0) {
#pragma unroll
        for (int i = 0; i < 4; i++)
            out[pbase + quad*4 + i] = rsum[i];
    }
}

// ---------------------------------------------------------------------------
extern "C" void kernel_launch(void* const* d_in, const int* in_sizes, int n_in,
                              void* d_out, int out_size, void* d_ws, size_t ws_size,
                              hipStream_t stream) {
    const float* x      = (const float*)d_in[0];
    const float* t      = (const float*)d_in[1];
    const float* alpha  = (const float*)d_in[2];
    const float* tab_s  = (const float*)d_in[3];
    const float* ws_in  = (const float*)d_in[4];
    const float* ws_hid = (const float*)d_in[5];
    const float* ws_out = (const float*)d_in[6];
    const float* tab_d  = (const float*)d_in[7];
    const float* wd_in  = (const float*)d_in[8];
    const float* wd_hid = (const float*)d_in[9];
    const float* wd_out = (const float*)d_in[10];
    const float* w1_in  = (const float*)d_in[11];
    const float* w1_hid = (const float*)d_in[12];
    const float* w1_out = (const float*)d_in[13];
    const float* w2_in  = (const float*)d_in[14];
    const float* w2_hid = (const float*)d_in[15];
    const float* w2_out = (const float*)d_in[16];
    float* out = (float*)d_out;

    char* ws = (char*)d_ws;
    _Float16* Wfrag = (_Float16*)ws;                       // 139264 B
    uint2*    Tc    = (uint2*)(ws + 139264);               // 64 MiB combined table
    uint32_t* EncS  = (uint32_t*)(ws + 139264 + 67108864); // 32 MiB
    uint32_t* EncD  = EncS + (size_t)LVLS * NPTS;          // 32 MiB
    size_t needed = 139264 + 67108864 + 2ull * 33554432ull;
    if (ws_size < needed) return;

    WPtrs wp;
    wp.p[0] = ws_in;  wp.p[1] = ws_hid; wp.p[2] = ws_out;
    wp.p[3] = wd_in;  wp.p[4] = wd_hid; wp.p[5] = wd_out;
    wp.p[6] = w1_in;  wp.p[7] = w1_hid; wp.p[8] = w1_out;
    wp.p[9] = w2_in;  wp.p[10] = w2_hid;

    k_weights<<<272,   256, 0, stream>>>(wp, Wfrag);
    k_tables <<<32768, 256, 0, stream>>>(tab_s, tab_d, t, Tc);
    k_encode <<<2048,  256, 0, stream>>>(x, Tc, EncS, EncD);
    k_mlp    <<<NPTS/64, 256, 0, stream>>>(EncS, EncD, Wfrag, alpha, w2_out, out);
}